// Round 4
// baseline (370.539 us; speedup 1.0000x reference)
//
#include <hip/hip_runtime.h>
#include <hip/hip_bf16.h>

// Problem constants (match reference file)
constexpr int K    = 8192;
constexpr int N4   = 6144;    // int4 rows
constexpr int N8   = 2048;    // uint8 rows
constexpr int NT   = N4 + N8; // 8192 output columns
constexpr int NG   = K / 128; // 64 groups per int4 row
constexpr int SPLITS = 16;    // k-splits per n-tile
constexpr int CPS    = 16;    // 32-k chunks per split (16*32 = 512 k)

typedef short  short8  __attribute__((ext_vector_type(8)));
typedef float  floatx4 __attribute__((ext_vector_type(4)));

__device__ inline short f2bf(float f) {
    __hip_bfloat16 h = __float2bfloat16(f);   // RNE
    return __builtin_bit_cast(short, h);
}

// ---------------------------------------------------------------------------
// Prep: x2bf = bf16(x/awq) stored in MFMA A-fragment order:
//   x2bf[c*512 + lane*8 + j] = X[m = lane&15][k = c*32 + (lane>>4)*8 + j]
// Also: fwd = inverse of inv_perm ; out = bias broadcast (atomics add on top).
// ---------------------------------------------------------------------------
__global__ void prep_kernel(const float* __restrict__ x,
                            const float* __restrict__ awq,
                            const int*   __restrict__ inv_perm,
                            const float* __restrict__ bias,
                            short* __restrict__ x2bf,
                            int*   __restrict__ fwd,
                            float* __restrict__ out) {
    const int tid  = blockIdx.x * blockDim.x + threadIdx.x;   // 0..131071
    const int c    = tid >> 9;
    const int rem  = tid & 511;
    const int lane = rem >> 3;
    const int j    = rem & 7;
    const int m    = lane & 15;
    const int k    = c * 32 + (lane >> 4) * 8 + j;
    x2bf[tid] = f2bf(x[m * K + k] / awq[k]);
    out[tid]  = bias[tid & (NT - 1)];
    if (tid < NT) fwd[inv_perm[tid]] = tid;
}

// ---------------------------------------------------------------------------
// Barrier-free MFMA GEMV. One wave = one 16-row n-tile x one 512-k split.
// B-fragment (weights) is dequantized inline to bf16:
//   int4 rows : wf = w*s - 8s      (group scale s, uniform per 32-k chunk)
//   uint8 rows: wf = w - 128       (exact in bf16; s8 applied in epilogue;
//               algebraic merge of hi/lo nibbles + 8*s*sum_x correction)
// D[m = (lane>>4)*4 + r][n = nb + (lane&15)] accumulated over splits via
// unsafeAtomicAdd into out (pre-initialized with bias).
// ---------------------------------------------------------------------------
__global__ __launch_bounds__(256)
void qgemv_kernel(const short* __restrict__ xf,
                  const int*   __restrict__ w4,
                  const float* __restrict__ s4,
                  const int*   __restrict__ w8,
                  const float* __restrict__ s8,
                  const int*   __restrict__ fwd,
                  float* __restrict__ out) {
    const int t    = threadIdx.x;
    const int lane = t & 63;
    const int wid  = blockIdx.x * 4 + (t >> 6);
    const int tile = wid >> 4;          // 0..511
    const int spl  = wid & (SPLITS - 1);
    const int nb   = tile * 16;
    const int i    = lane & 15;
    const int q    = lane >> 4;
    const int row  = nb + i;            // this lane's weight row / output col

    const bool is4 = (nb < N4);
    const int* wr  = is4 ? (w4 + (size_t)row * K + q * 8)
                         : (w8 + (size_t)(row - N4) * K + q * 8);
    const int c0   = spl * CPS;

    floatx4 acc = {0.f, 0.f, 0.f, 0.f};

    #pragma unroll 1
    for (int gi = 0; gi < 4; ++gi) {                // 4 scale-groups per split
        const int g   = (c0 >> 2) + gi;
        const float s  = is4 ? s4[row * NG + g] : 1.f;
        const float sb = is4 ? -8.f * s : -128.f;

        #pragma unroll
        for (int ci = 0; ci < 4; ++ci) {            // 4 chunks per group
            const int c = c0 + gi * 4 + ci;
            const int4 wa = *(const int4*)(wr + (size_t)c * 32);
            const int4 wb = *(const int4*)(wr + (size_t)c * 32 + 4);

            short8 bfrag;
            bfrag[0] = f2bf((float)wa.x * s + sb);
            bfrag[1] = f2bf((float)wa.y * s + sb);
            bfrag[2] = f2bf((float)wa.z * s + sb);
            bfrag[3] = f2bf((float)wa.w * s + sb);
            bfrag[4] = f2bf((float)wb.x * s + sb);
            bfrag[5] = f2bf((float)wb.y * s + sb);
            bfrag[6] = f2bf((float)wb.z * s + sb);
            bfrag[7] = f2bf((float)wb.w * s + sb);

            const short8 afrag = *(const short8*)(xf + (size_t)c * 512 + lane * 8);

            acc = __builtin_amdgcn_mfma_f32_16x16x32_bf16(afrag, bfrag, acc, 0, 0, 0);
        }
    }

    // ---- epilogue: scale (int8 path) + permute + atomic accumulate ----
    const float sc = is4 ? 1.f : s8[row - N4];
    const int   d  = fwd[row];
    #pragma unroll
    for (int r = 0; r < 4; ++r) {
        const int m = q * 4 + r;
        unsafeAtomicAdd(&out[(size_t)m * NT + d], acc[r] * sc);
    }
}

// ---------------------------------------------------------------------------
extern "C" void kernel_launch(void* const* d_in, const int* in_sizes, int n_in,
                              void* d_out, int out_size, void* d_ws, size_t ws_size,
                              hipStream_t stream) {
    const float* x        = (const float*)d_in[0];
    const int*   w_int4   = (const int*)  d_in[1];
    const float* s_int4   = (const float*)d_in[2];
    const int*   w_uint8  = (const int*)  d_in[3];
    const float* s_int8   = (const float*)d_in[4];
    const float* awq      = (const float*)d_in[5];
    const float* bias     = (const float*)d_in[6];
    const int*   inv_perm = (const int*)  d_in[7];
    // d_in[8] = group_size (==128), compile-time constant here

    short* x2bf = (short*)d_ws;                                  // 256 KB
    int*   fwd  = (int*)((char*)d_ws + (size_t)16 * K * sizeof(short)); // 32 KB

    prep_kernel<<<(16 * K) / 256, 256, 0, stream>>>(x, awq, inv_perm, bias,
                                                    x2bf, fwd, (float*)d_out);
    // 512 tiles * 16 splits = 8192 waves = 2048 blocks of 4 waves
    qgemv_kernel<<<2048, 256, 0, stream>>>(x2bf, w_int4, s_int4,
                                           w_uint8, s_int8, fwd,
                                           (float*)d_out);
}

// Round 5
// 337.266 us; speedup vs baseline: 1.0987x; 1.0987x over previous
//
#include <hip/hip_runtime.h>
#include <hip/hip_bf16.h>

// Problem constants (match reference file)
constexpr int K    = 8192;
constexpr int N4   = 6144;    // int4 rows
constexpr int N8   = 2048;    // uint8 rows
constexpr int NT   = N4 + N8; // 8192 output columns
constexpr int NG   = K / 128; // 64 groups per int4 row

typedef short  short8  __attribute__((ext_vector_type(8)));
typedef float  floatx4 __attribute__((ext_vector_type(4)));

__device__ inline short f2bf(float f) {
    __hip_bfloat16 h = __float2bfloat16(f);   // RNE
    return __builtin_bit_cast(short, h);
}

// ---------------------------------------------------------------------------
// Prep: x2bf = bf16(x/awq) stored in MFMA A-fragment order:
//   x2bf[c*512 + lane*8 + j] = X[m = lane&15][k = c*32 + (lane>>4)*8 + j]
// Also: fwd = inverse of inv_perm.
// ---------------------------------------------------------------------------
__global__ void prep_kernel(const float* __restrict__ x,
                            const float* __restrict__ awq,
                            const int*   __restrict__ inv_perm,
                            short* __restrict__ x2bf,
                            int*   __restrict__ fwd) {
    const int tid  = blockIdx.x * blockDim.x + threadIdx.x;   // 0..131071
    const int c    = tid >> 9;
    const int rem  = tid & 511;
    const int lane = rem >> 3;
    const int j    = rem & 7;
    const int m    = lane & 15;
    const int k    = c * 32 + (lane >> 4) * 8 + j;
    x2bf[tid] = f2bf(x[m * K + k] / awq[k]);
    if (tid < NT) fwd[inv_perm[tid]] = tid;
}

// ---------------------------------------------------------------------------
// Single-pass MFMA GEMV, no atomics, no split-K partials.
// Block = 4 waves = one 16-row tile; wave w covers k in [w*2048, w*2048+2048)
// as 64 chunks of 32 k. Explicit 2-stage pipeline over 4-chunk groups keeps
// 12 16B loads in flight per wave while the previous group dequantizes+MFMAs
// (fine-grained vmcnt, AITER-style - no barrier in the K loop).
//   int4 rows : wf = w*s - 8s      (group scale s, one group per 4 chunks)
//   uint8 rows: wf = w - 128       (exact in bf16; s8 applied in epilogue;
//               algebraic merge of hi/lo nibbles + 8*s*sum_x correction)
// Epilogue: 4KB LDS cross-wave reduce, then 256 threads apply s8/perm/bias
// and write each output element exactly once.
// ---------------------------------------------------------------------------
__global__ __launch_bounds__(256)
void qgemv_kernel(const short* __restrict__ xf,
                  const int*   __restrict__ w4,
                  const float* __restrict__ s4,
                  const int*   __restrict__ w8,
                  const float* __restrict__ s8,
                  const int*   __restrict__ fwd,
                  const float* __restrict__ bias,
                  float* __restrict__ out) {
    __shared__ float lds[4 * 256];

    const int t    = threadIdx.x;
    const int lane = t & 63;
    const int w    = t >> 6;            // wave 0..3
    const int nb   = blockIdx.x * 16;   // tile base row
    const int i    = lane & 15;
    const int q    = lane >> 4;
    const int row  = nb + i;            // this lane's weight row

    const bool is4 = (nb < N4);
    const int*   wp = (is4 ? (w4 + (size_t)row * K)
                           : (w8 + (size_t)(row - N4) * K))
                      + (size_t)w * 2048 + q * 8;          // + chunk*32 later
    const short* xw = xf + (size_t)w * 64 * 512 + lane * 8; // + chunk*512 later
    const float* sp = is4 ? (s4 + (size_t)row * NG + w * 16) : nullptr; // + g

    floatx4 acc = {0.f, 0.f, 0.f, 0.f};

    int4   wbA[8], wbB[8];
    short8 abA[4], abB[4];
    float  sA = 0.f, sB = 0.f;

    auto loadg = [&](int g, int4* wb, short8* ab, float& s) {
        #pragma unroll
        for (int c = 0; c < 4; ++c) {
            const size_t co = (size_t)(g * 4 + c);
            wb[2 * c]     = *(const int4*)(wp + co * 32);
            wb[2 * c + 1] = *(const int4*)(wp + co * 32 + 4);
            ab[c]         = *(const short8*)(xw + co * 512);
        }
        if (is4) s = sp[g];
    };

    auto compg = [&](const int4* wb, const short8* ab, float s) {
        const float sc = is4 ? s : 1.f;
        const float sb = is4 ? -8.f * s : -128.f;
        #pragma unroll
        for (int c = 0; c < 4; ++c) {
            const int4 wa = wb[2 * c];
            const int4 wz = wb[2 * c + 1];
            short8 bf;
            bf[0] = f2bf((float)wa.x * sc + sb);
            bf[1] = f2bf((float)wa.y * sc + sb);
            bf[2] = f2bf((float)wa.z * sc + sb);
            bf[3] = f2bf((float)wa.w * sc + sb);
            bf[4] = f2bf((float)wz.x * sc + sb);
            bf[5] = f2bf((float)wz.y * sc + sb);
            bf[6] = f2bf((float)wz.z * sc + sb);
            bf[7] = f2bf((float)wz.w * sc + sb);
            acc = __builtin_amdgcn_mfma_f32_16x16x32_bf16(ab[c], bf, acc, 0, 0, 0);
        }
    };

    // 16 groups of 4 chunks, 2-stage manual pipeline (A/B buffers).
    loadg(0, wbA, abA, sA);
    #pragma unroll 1
    for (int g = 0; g < 16; g += 2) {
        const int g1 = (g + 1 < 16) ? g + 1 : 15;
        loadg(g1, wbB, abB, sB);
        compg(wbA, abA, sA);
        const int g2 = (g + 2 < 16) ? g + 2 : 15;   // last iter: dummy reload
        loadg(g2, wbA, abA, sA);
        compg(wbB, abB, sB);
    }

    // ---- cross-wave reduce + fused scale/perm/bias writeout ----
    #pragma unroll
    for (int r = 0; r < 4; ++r)
        lds[w * 256 + (q * 4 + r) * 16 + i] = acc[r];
    __syncthreads();

    {
        const int m  = t >> 4;     // 0..15 (batch row)
        const int i2 = t & 15;     // 0..15 (tile col)
        const float v = lds[0 * 256 + t] + lds[1 * 256 + t]
                      + lds[2 * 256 + t] + lds[3 * 256 + t];
        const int n  = nb + i2;
        const float sc = is4 ? 1.f : s8[n - N4];
        const int d  = fwd[n];
        out[(size_t)m * NT + d] = v * sc + bias[d];
    }
}

// ---------------------------------------------------------------------------
extern "C" void kernel_launch(void* const* d_in, const int* in_sizes, int n_in,
                              void* d_out, int out_size, void* d_ws, size_t ws_size,
                              hipStream_t stream) {
    const float* x        = (const float*)d_in[0];
    const int*   w_int4   = (const int*)  d_in[1];
    const float* s_int4   = (const float*)d_in[2];
    const int*   w_uint8  = (const int*)  d_in[3];
    const float* s_int8   = (const float*)d_in[4];
    const float* awq      = (const float*)d_in[5];
    const float* bias     = (const float*)d_in[6];
    const int*   inv_perm = (const int*)  d_in[7];
    // d_in[8] = group_size (==128), compile-time constant here

    short* x2bf = (short*)d_ws;                                       // 256 KB
    int*   fwd  = (int*)((char*)d_ws + (size_t)16 * K * sizeof(short)); // 32 KB

    prep_kernel<<<(16 * K) / 256, 256, 0, stream>>>(x, awq, inv_perm, x2bf, fwd);
    qgemv_kernel<<<NT / 16, 256, 0, stream>>>(x2bf, w_int4, s_int4,
                                              w_uint8, s_int8, fwd, bias,
                                              (float*)d_out);
}